// Round 17
// baseline (716.862 us; speedup 1.0000x reference)
//
#include <hip/hip_runtime.h>

#define BROWS 32768
#define DDIM 1024

typedef __bf16 bf16x8v __attribute__((ext_vector_type(8)));
typedef float f32x4v __attribute__((ext_vector_type(4)));

__device__ __forceinline__ float bf2f(unsigned short u) {
  union { unsigned int i; float f; } w; w.i = ((unsigned int)u) << 16; return w.f;
}
__device__ __forceinline__ unsigned short f2bf(float f) {
  union { float f; unsigned int i; } w; w.f = f;
  w.i += 0x7fffu + ((w.i >> 16) & 1u);   // RNE
  return (unsigned short)(w.i >> 16);
}

__device__ __forceinline__ void gl_lds16(const void* g, void* l) {
  __builtin_amdgcn_global_load_lds((const __attribute__((address_space(1))) void*)g,
                                   (__attribute__((address_space(3))) void*)l, 16, 0, 0);
}

__device__ __forceinline__ int xcd_swz(int bid, int nwg) {
  return (bid & 7) * (nwg >> 3) + (bid >> 3);
}

// 32-col-period swizzle: element (row,col) stored at col^((row&3)<<3) within its
// 32-col block. Involution; 16B-chunk granular (chunk' = chunk ^ (row&3)).
__device__ __forceinline__ int swz32(int row, int col) {
  return (col & ~31) | ((col & 31) ^ ((row & 3) << 3));
}

// graph & smiles f32 -> bf16, PRE-SWIZZLED (swz32).
__global__ __launch_bounds__(256) void cvt_x(const float* __restrict__ g,
                                             const float* __restrict__ s,
                                             unsigned short* __restrict__ xg,
                                             unsigned short* __restrict__ xs) {
  const size_t N = (size_t)BROWS * DDIM;
  size_t i = ((size_t)blockIdx.x * 256 + threadIdx.x) * 4;
  const float* src = (i < N) ? g : s;
  unsigned short* dst = (i < N) ? xg : xs;
  size_t off = (i < N) ? i : i - N;
  int row = (int)(off >> 10), col = (int)(off & 1023);
  float4 v = *(const float4*)&src[off];
  union { uint2 q; unsigned short h[4]; } u;
  u.h[0] = f2bf(v.x); u.h[1] = f2bf(v.y); u.h[2] = f2bf(v.z); u.h[3] = f2bf(v.w);
  *(uint2*)&dst[(size_t)row * DDIM + swz32(row, col)] = u.q;
}

// Wg f32 [1024][2048] -> bf16, PRE-SWIZZLED (swz32).
__global__ __launch_bounds__(256) void cvt_wg(const float* __restrict__ s,
                                              unsigned short* __restrict__ d) {
  int i = (blockIdx.x * 256 + threadIdx.x) * 4;
  int row = i >> 11, col = i & 2047;
  float4 v = *(const float4*)&s[i];
  union { uint2 q; unsigned short h[4]; } u;
  u.h[0] = f2bf(v.x); u.h[1] = f2bf(v.y); u.h[2] = f2bf(v.z); u.h[3] = f2bf(v.w);
  *(uint2*)&d[(size_t)row * 2048 + swz32(row, col)] = u.q;
}

// bc = Wo @ bv + bo
__global__ __launch_bounds__(256) void bias_combine(
    const float* __restrict__ Wo_gs, const float* __restrict__ bv_gs,
    const float* __restrict__ bo_gs,
    const float* __restrict__ Wo_sg, const float* __restrict__ bv_sg,
    const float* __restrict__ bo_sg,
    float* __restrict__ bc_gs, float* __restrict__ bc_sg) {
  int gid = blockIdx.x * 256 + threadIdx.x;
  int pair = gid >> 10, j = gid & 1023;
  const float* Wo = pair ? Wo_sg : Wo_gs;
  const float* bv = pair ? bv_sg : bv_gs;
  const float* bo = pair ? bo_sg : bo_gs;
  float s = 0.f;
  for (int k = 0; k < DDIM; k += 4) {
    float4 w = *(const float4*)&Wo[(size_t)j * DDIM + k];
    float4 b = *(const float4*)&bv[k];
    s += w.x * b.x + w.y * b.y + w.z * b.z + w.w * b.w;
  }
  float* bc = pair ? bc_sg : bc_gs;
  bc[j] = s + bo[j];
}

// f32 -> bf16 [128][32] LDS tile (combine kernel, linear layout).
__device__ __forceinline__ void stage_f32_32(const float* __restrict__ src, int ldk,
                                             int row0, int k0, unsigned short* lds, int tid) {
  const int sr = tid >> 2, sc = (tid & 3) * 8;
#pragma unroll
  for (int h = 0; h < 2; ++h) {
    const float* g = &src[(size_t)(row0 + h * 64 + sr) * ldk + k0 + sc];
    float4 va = ((const float4*)g)[0];
    float4 vb = ((const float4*)g)[1];
    union { uint4 q; unsigned short hh[8]; } u;
    u.hh[0] = f2bf(va.x); u.hh[1] = f2bf(va.y); u.hh[2] = f2bf(va.z); u.hh[3] = f2bf(va.w);
    u.hh[4] = f2bf(vb.x); u.hh[5] = f2bf(vb.y); u.hh[6] = f2bf(vb.z); u.hh[7] = f2bf(vb.w);
    *(uint4*)&lds[(h * 64 + sr) * 32 + sc] = u.q;
  }
}

__device__ __forceinline__ void mfma_tile32(const unsigned short* As, const unsigned short* Bs,
                                            int ab, int bb, f32x4v acc[4][4]) {
  const bf16x8v* Av = reinterpret_cast<const bf16x8v*>(As);
  const bf16x8v* Bv = reinterpret_cast<const bf16x8v*>(Bs);
  bf16x8v af[4], bfr[4];
#pragma unroll
  for (int m = 0; m < 4; ++m) af[m] = Av[ab + m * 64];
#pragma unroll
  for (int n = 0; n < 4; ++n) bfr[n] = Bv[bb + n * 64];
#pragma unroll
  for (int m = 0; m < 4; ++m)
#pragma unroll
    for (int n = 0; n < 4; ++n)
      acc[m][n] = __builtin_amdgcn_mfma_f32_16x16x32_bf16(af[m], bfr[n], acc[m][n], 0, 0, 0);
}

// Wc = Wo @ Wv (1024^3 NN, f32 in) — writes Wc PRE-SWIZZLED (swz32).
__global__ __launch_bounds__(256) void combine_kernel(
    const float* __restrict__ Wo_gs, const float* __restrict__ Wv_gs,
    const float* __restrict__ Wo_sg, const float* __restrict__ Wv_sg,
    unsigned short* __restrict__ Wc_gs, unsigned short* __restrict__ Wc_sg) {
  const int pair = blockIdx.y;
  const float* Wo = pair ? Wo_sg : Wo_gs;
  const float* Wv = pair ? Wv_sg : Wv_gs;
  unsigned short* Wc = pair ? Wc_sg : Wc_gs;
  const int mt = blockIdx.x >> 3, nt = blockIdx.x & 7;
  const int row0 = mt * 128, col0 = nt * 128;

  __shared__ __align__(16) unsigned short As[128 * 32];
  __shared__ __align__(16) unsigned short Bt[128 * 32];

  const int tid = threadIdx.x;
  const int lane = tid & 63, wave = tid >> 6;
  const int wr = wave >> 1, wc = wave & 1;
  const int lr = lane & 15, lk = lane >> 4;

  f32x4v acc[4][4] = {};
  const int ab = (wr * 64 + lr) * 4 + lk;
  const int bb = (wc * 64 + lr) * 4 + lk;

  for (int tt = 0; tt < 32; ++tt) {
    const int t0 = tt * 32;
    __syncthreads();
    stage_f32_32(Wo, DDIM, row0, t0, As, tid);
#pragma unroll
    for (int h = 0; h < 2; ++h) {
      int chunk = h * 256 + tid;
      int t = chunk >> 4;
      int c8 = (chunk & 15) * 8;
      const float* g = &Wv[(size_t)(t0 + t) * DDIM + col0 + c8];
      float4 va = ((const float4*)g)[0];
      float4 vb = ((const float4*)g)[1];
      float vv[8] = {va.x, va.y, va.z, va.w, vb.x, vb.y, vb.z, vb.w};
#pragma unroll
      for (int e = 0; e < 8; ++e) Bt[(c8 + e) * 32 + t] = f2bf(vv[e]);
    }
    __syncthreads();
    mfma_tile32(As, Bt, ab, bb, acc);
  }

#pragma unroll
  for (int n = 0; n < 4; ++n) {
    int col = col0 + wc * 64 + n * 16 + lr;
#pragma unroll
    for (int m = 0; m < 4; ++m) {
      int rbase = row0 + wr * 64 + m * 16 + lk * 4;
#pragma unroll
      for (int r = 0; r < 4; ++r)
        Wc[(size_t)(rbase + r) * DDIM + swz32(rbase + r, col)] = f2bf(acc[m][n][r]);
    }
  }
}

// ====== 128x128 BK=32 pipelined GEMM, 3 blocks/CU (48 KB LDS) ======
// 4 waves (2Mx2N), per-wave 64x64 acc[4][4]. A: 4 slots [128][32] (dist 3);
// B: 2 slots (dist 1). Per K-step: vmcnt(N) -> s_barrier -> issue B(kt+1)x2 +
// A(kt+3)x2 -> 8 frag reads -> setprio{16 MFMA}. Ledger (FIFO, B-then-A per
// step): kt=0 -> vmcnt(4); steady -> vmcnt(2) (keeps A(kt+2) in flight);
// kt>=NT-2 -> vmcnt(0). WAR-free: write slots (kt+3)&3 / (kt+1)&1 differ from
// read slots; prior step's ds_reads drained (lgkmcnt before MFMA) pre-barrier.

// Z = bf16( Xb @ Wc^T + bc + residb ), all operand arrays swz32.
__global__ __launch_bounds__(256, 3) void gemm_branch8(
    const unsigned short* __restrict__ Xs_b, const unsigned short* __restrict__ Xg_b,
    const unsigned short* __restrict__ Wc_gs, const unsigned short* __restrict__ Wc_sg,
    const float* __restrict__ bc_gs, const float* __restrict__ bc_sg,
    unsigned short* __restrict__ Zg, unsigned short* __restrict__ Zs) {
  const int pair = blockIdx.y;
  const unsigned short* X = pair ? Xg_b : Xs_b;
  const unsigned short* residb = pair ? Xs_b : Xg_b;
  const unsigned short* Wc = pair ? Wc_sg : Wc_gs;
  const float* bc = pair ? bc_sg : bc_gs;
  unsigned short* Z = pair ? Zs : Zg;

  const int bid = xcd_swz(blockIdx.x, 2048);
  const int mt = bid >> 3, nt = bid & 7;
  const int row0 = mt * 128, col0 = nt * 128;
  const int NT = 32;

  __shared__ __align__(16) unsigned short As[4][128 * 32];   // 32 KB
  __shared__ __align__(16) unsigned short Bs[2][128 * 32];   // 16 KB

  const int tid = threadIdx.x;
  const int lane = tid & 63, wave = tid >> 6;
  const int wm = wave >> 1, wn = wave & 1;
  const int lr = lane & 15, lk = lane >> 4;

  f32x4v acc[4][4] = {};

  auto stageB = [&](int kt) {
#pragma unroll
    for (int j = 0; j < 2; ++j) {
      int e = (j * 256 + tid) * 8;
      int row = e >> 5, cp = e & 31;
      gl_lds16(&Wc[(size_t)(col0 + row) * DDIM + kt * 32 + cp], &Bs[kt & 1][e]);
    }
  };
  auto stageA = [&](int kt) {
#pragma unroll
    for (int j = 0; j < 2; ++j) {
      int e = (j * 256 + tid) * 8;
      int row = e >> 5, cp = e & 31;
      gl_lds16(&X[(size_t)(row0 + row) * DDIM + kt * 32 + cp], &As[kt & 3][e]);
    }
  };

  // Prologue: B(0), A(0), A(1), A(2)  (FIFO matches loop waits).
  stageB(0); stageA(0); stageA(1); stageA(2);

  for (int kt = 0; kt < NT; ++kt) {
    if (kt == 0)          asm volatile("s_waitcnt vmcnt(4)" ::: "memory");
    else if (kt < NT - 2) asm volatile("s_waitcnt vmcnt(2)" ::: "memory");
    else                  asm volatile("s_waitcnt vmcnt(0)" ::: "memory");
    asm volatile("s_barrier" ::: "memory");
    if (kt + 1 < NT) stageB(kt + 1);
    if (kt + 3 < NT) stageA(kt + 3);

    const unsigned short* Ak = As[kt & 3];
    const unsigned short* Bk = Bs[kt & 1];
    bf16x8v av[4], bv[4];
#pragma unroll
    for (int n = 0; n < 4; ++n) {
      int row = wn * 64 + n * 16 + lr;
      bv[n] = *(const bf16x8v*)&Bk[row * 32 + ((lk ^ (row & 3)) * 8)];
    }
#pragma unroll
    for (int m = 0; m < 4; ++m) {
      int row = wm * 64 + m * 16 + lr;
      av[m] = *(const bf16x8v*)&Ak[row * 32 + ((lk ^ (row & 3)) * 8)];
    }
    __builtin_amdgcn_s_setprio(1);
#pragma unroll
    for (int m = 0; m < 4; ++m)
#pragma unroll
      for (int n = 0; n < 4; ++n)
        acc[m][n] = __builtin_amdgcn_mfma_f32_16x16x32_bf16(av[m], bv[n], acc[m][n], 0, 0, 0);
    __builtin_amdgcn_s_setprio(0);
  }

#pragma unroll
  for (int n = 0; n < 4; ++n) {
    int col = col0 + wn * 64 + n * 16 + lr;
    float bcv = bc[col];
#pragma unroll
    for (int m = 0; m < 4; ++m) {
      int rb = row0 + wm * 64 + m * 16 + lk * 4;
#pragma unroll
      for (int r = 0; r < 4; ++r) {
        int row = rb + r;
        size_t idx = (size_t)row * DDIM + swz32(row, col);
        Z[idx] = f2bf(acc[m][n][r] + bcv + bf2f(residb[idx]));
      }
    }
  }
}

// gate = sigmoid([fg,fs] @ WgB^T + bg); f32 out at true columns.
__global__ __launch_bounds__(256, 3) void gemm_gate8(
    const unsigned short* __restrict__ fg, const unsigned short* __restrict__ fs,
    const unsigned short* __restrict__ WgB, const float* __restrict__ bg,
    float* __restrict__ out0, float* __restrict__ out1) {
  const int bid = xcd_swz(blockIdx.x, 2048);
  const int mt = bid >> 3, nt = bid & 7;
  const int row0 = mt * 128, col0 = nt * 128;
  const int NT = 64;

  __shared__ __align__(16) unsigned short As[4][128 * 32];
  __shared__ __align__(16) unsigned short Bs[2][128 * 32];

  const int tid = threadIdx.x;
  const int lane = tid & 63, wave = tid >> 6;
  const int wm = wave >> 1, wn = wave & 1;
  const int lr = lane & 15, lk = lane >> 4;

  f32x4v acc[4][4] = {};

  auto stageB = [&](int kt) {
#pragma unroll
    for (int j = 0; j < 2; ++j) {
      int e = (j * 256 + tid) * 8;
      int row = e >> 5, cp = e & 31;
      gl_lds16(&WgB[(size_t)(col0 + row) * 2048 + kt * 32 + cp], &Bs[kt & 1][e]);
    }
  };
  auto stageA = [&](int kt) {
    const unsigned short* asrc = (kt < 32) ? fg : fs;
    int ak0 = (kt & 31) * 32;
#pragma unroll
    for (int j = 0; j < 2; ++j) {
      int e = (j * 256 + tid) * 8;
      int row = e >> 5, cp = e & 31;
      gl_lds16(&asrc[(size_t)(row0 + row) * DDIM + ak0 + cp], &As[kt & 3][e]);
    }
  };

  stageB(0); stageA(0); stageA(1); stageA(2);

  for (int kt = 0; kt < NT; ++kt) {
    if (kt == 0)          asm volatile("s_waitcnt vmcnt(4)" ::: "memory");
    else if (kt < NT - 2) asm volatile("s_waitcnt vmcnt(2)" ::: "memory");
    else                  asm volatile("s_waitcnt vmcnt(0)" ::: "memory");
    asm volatile("s_barrier" ::: "memory");
    if (kt + 1 < NT) stageB(kt + 1);
    if (kt + 3 < NT) stageA(kt + 3);

    const unsigned short* Ak = As[kt & 3];
    const unsigned short* Bk = Bs[kt & 1];
    bf16x8v av[4], bv[4];
#pragma unroll
    for (int n = 0; n < 4; ++n) {
      int row = wn * 64 + n * 16 + lr;
      bv[n] = *(const bf16x8v*)&Bk[row * 32 + ((lk ^ (row & 3)) * 8)];
    }
#pragma unroll
    for (int m = 0; m < 4; ++m) {
      int row = wm * 64 + m * 16 + lr;
      av[m] = *(const bf16x8v*)&Ak[row * 32 + ((lk ^ (row & 3)) * 8)];
    }
    __builtin_amdgcn_s_setprio(1);
#pragma unroll
    for (int m = 0; m < 4; ++m)
#pragma unroll
      for (int n = 0; n < 4; ++n)
        acc[m][n] = __builtin_amdgcn_mfma_f32_16x16x32_bf16(av[m], bv[n], acc[m][n], 0, 0, 0);
    __builtin_amdgcn_s_setprio(0);
  }

#pragma unroll
  for (int n = 0; n < 4; ++n) {
    int col = col0 + wn * 64 + n * 16 + lr;
    float bgv = bg[col];
#pragma unroll
    for (int m = 0; m < 4; ++m) {
      int rb = row0 + wm * 64 + m * 16 + lk * 4;
#pragma unroll
      for (int r = 0; r < 4; ++r) {
        int row = rb + r;
        size_t sidx = (size_t)row * DDIM + swz32(row, col);
        size_t tidx = (size_t)row * DDIM + col;
        float g = 1.f / (1.f + __expf(-(acc[m][n][r] + bgv)));
        float a = bf2f(fg[sidx]), b = bf2f(fs[sidx]);
        out0[tidx] = g * a + (1.f - g) * b;
        out1[tidx] = g;
      }
    }
  }
}

// In-place LayerNorm over swz32 Z rows (gamma/beta index XORed per 4-group block).
__global__ __launch_bounds__(256) void ln_kernel(
    unsigned short* __restrict__ Z,
    const float* __restrict__ gam_g, const float* __restrict__ bet_g,
    const float* __restrict__ gam_s, const float* __restrict__ bet_s) {
  int row = blockIdx.x * 4 + (threadIdx.x >> 6);
  int lane = threadIdx.x & 63;
  const float* gam = (row < BROWS) ? gam_g : gam_s;
  const float* bet = (row < BROWS) ? bet_g : bet_s;
  unsigned short* zr = Z + (size_t)row * DDIM;

  uint4 v0 = *(const uint4*)(zr + lane * 8);
  uint4 v1 = *(const uint4*)(zr + 512 + lane * 8);
  const unsigned short* u0 = (const unsigned short*)&v0;
  const unsigned short* u1 = (const unsigned short*)&v1;
  float x[16];
  float s = 0.f, sq = 0.f;
#pragma unroll
  for (int e = 0; e < 8; ++e) { x[e] = bf2f(u0[e]); x[8 + e] = bf2f(u1[e]); }
#pragma unroll
  for (int i = 0; i < 16; ++i) { s += x[i]; sq += x[i] * x[i]; }
#pragma unroll
  for (int o = 32; o; o >>= 1) { s += __shfl_xor(s, o); sq += __shfl_xor(sq, o); }
  float mu = s * (1.f / 1024.f);
  float var = sq * (1.f / 1024.f) - mu * mu;
  float rstd = rsqrtf(var + 1e-5f);

  int lane2 = (lane & ~3) | ((lane & 3) ^ (row & 3));
  float4 g0 = *(const float4*)(gam + lane2 * 8);
  float4 g1 = *(const float4*)(gam + lane2 * 8 + 4);
  float4 g2 = *(const float4*)(gam + 512 + lane2 * 8);
  float4 g3 = *(const float4*)(gam + 512 + lane2 * 8 + 4);
  float4 b0 = *(const float4*)(bet + lane2 * 8);
  float4 b1 = *(const float4*)(bet + lane2 * 8 + 4);
  float4 b2 = *(const float4*)(bet + 512 + lane2 * 8);
  float4 b3 = *(const float4*)(bet + 512 + lane2 * 8 + 4);
  float gg[16] = {g0.x,g0.y,g0.z,g0.w,g1.x,g1.y,g1.z,g1.w,
                  g2.x,g2.y,g2.z,g2.w,g3.x,g3.y,g3.z,g3.w};
  float bb[16] = {b0.x,b0.y,b0.z,b0.w,b1.x,b1.y,b1.z,b1.w,
                  b2.x,b2.y,b2.z,b2.w,b3.x,b3.y,b3.z,b3.w};

  union { uint4 q; unsigned short h[8]; } o0, o1;
#pragma unroll
  for (int e = 0; e < 8; ++e) {
    o0.h[e] = f2bf((x[e] - mu) * rstd * gg[e] + bb[e]);
    o1.h[e] = f2bf((x[8 + e] - mu) * rstd * gg[8 + e] + bb[8 + e]);
  }
  *(uint4*)(zr + lane * 8) = o0.q;
  *(uint4*)(zr + 512 + lane * 8) = o1.q;
}

// Fallback gate (d_ws < 132 MiB): [128][64] tiles, swz32-aware chunk math.
__global__ __launch_bounds__(256) void gemm_gate_f32(
    const unsigned short* __restrict__ fg, const unsigned short* __restrict__ fs,
    const float* __restrict__ Wg, const float* __restrict__ bg,
    float* __restrict__ out0, float* __restrict__ out1) {
  const int bid = xcd_swz(blockIdx.x, 2048);
  const int mt = bid >> 3, nt = bid & 7;
  const int row0 = mt * 128, col0 = nt * 128;

  __shared__ __align__(16) unsigned short As[128 * 64];
  __shared__ __align__(16) unsigned short Bsh[128 * 64];

  const int tid = threadIdx.x;
  const int lane = tid & 63, wave = tid >> 6;
  const int wr = wave >> 1, wc = wave & 1;
  const int lr = lane & 15, lk = lane >> 4;

  f32x4v acc[4][4] = {};

  for (int kt = 0; kt < 32; ++kt) {
    const unsigned short* Asrc = (kt < 16) ? fg : fs;
    const int k0 = (kt & 15) * 64;
    const int kw = kt * 64;
    __syncthreads();
#pragma unroll
    for (int h = 0; h < 4; ++h) {
      int row = h * 32 + (tid >> 3);
      gl_lds16(&Asrc[(size_t)(row0 + row) * DDIM + k0 + (tid & 7) * 8], &As[h * 2048 + tid * 8]);
    }
#pragma unroll
    for (int h = 0; h < 4; ++h) {
      int row = h * 32 + (tid >> 3), c16 = tid & 7;
      const float* gsrc = &Wg[(size_t)(col0 + row) * 2048 + kw + c16 * 8];
      float4 va = ((const float4*)gsrc)[0];
      float4 vb = ((const float4*)gsrc)[1];
      union { uint4 q; unsigned short hh[8]; } u;
      u.hh[0] = f2bf(va.x); u.hh[1] = f2bf(va.y); u.hh[2] = f2bf(va.z); u.hh[3] = f2bf(va.w);
      u.hh[4] = f2bf(vb.x); u.hh[5] = f2bf(vb.y); u.hh[6] = f2bf(vb.z); u.hh[7] = f2bf(vb.w);
      int cst = (c16 & ~3) | ((c16 & 3) ^ (row & 3));
      *(uint4*)&Bsh[(row * 8 + cst) * 8] = u.q;
    }
    __syncthreads();
    const bf16x8v* Av = reinterpret_cast<const bf16x8v*>(As);
    const bf16x8v* Bv = reinterpret_cast<const bf16x8v*>(Bsh);
#pragma unroll
    for (int s = 0; s < 2; ++s) {
      bf16x8v af[4], bfr[4];
#pragma unroll
      for (int m = 0; m < 4; ++m) {
        int row = wr * 64 + m * 16 + lr;
        int c = s * 4 + lk;
        int u = (c & ~3) | ((c & 3) ^ (row & 3));
        af[m] = Av[row * 8 + u];
      }
#pragma unroll
      for (int n = 0; n < 4; ++n) {
        int row = wc * 64 + n * 16 + lr;
        int c = s * 4 + lk;
        int u = (c & ~3) | ((c & 3) ^ (row & 3));
        bfr[n] = Bv[row * 8 + u];
      }
#pragma unroll
      for (int m = 0; m < 4; ++m)
#pragma unroll
        for (int n = 0; n < 4; ++n)
          acc[m][n] = __builtin_amdgcn_mfma_f32_16x16x32_bf16(af[m], bfr[n], acc[m][n], 0, 0, 0);
    }
  }

#pragma unroll
  for (int n = 0; n < 4; ++n) {
    int col = col0 + wc * 64 + n * 16 + lr;
    float bgv = bg[col];
#pragma unroll
    for (int m = 0; m < 4; ++m) {
      int rbase = row0 + wr * 64 + m * 16 + lk * 4;
#pragma unroll
      for (int r = 0; r < 4; ++r) {
        int row = rbase + r;
        size_t sidx = (size_t)row * DDIM + swz32(row, col);
        size_t tidx = (size_t)row * DDIM + col;
        float g = 1.f / (1.f + __expf(-(acc[m][n][r] + bgv)));
        float a = bf2f(fg[sidx]), b = bf2f(fs[sidx]);
        out0[tidx] = g * a + (1.f - g) * b;
        out1[tidx] = g;
      }
    }
  }
}

extern "C" void kernel_launch(void* const* d_in, const int* in_sizes, int n_in,
                              void* d_out, int out_size, void* d_ws, size_t ws_size,
                              hipStream_t stream) {
  const float* graph  = (const float*)d_in[0];
  const float* smiles = (const float*)d_in[1];
  const float* Wv_gs  = (const float*)d_in[5];
  const float* bv_gs  = (const float*)d_in[8];
  const float* Wo_gs  = (const float*)d_in[9];
  const float* bo_gs  = (const float*)d_in[10];
  const float* Wv_sg  = (const float*)d_in[13];
  const float* bv_sg  = (const float*)d_in[16];
  const float* Wo_sg  = (const float*)d_in[17];
  const float* bo_sg  = (const float*)d_in[18];
  const float* ln_gg  = (const float*)d_in[19];
  const float* ln_gb  = (const float*)d_in[20];
  const float* ln_sg  = (const float*)d_in[21];
  const float* ln_sb  = (const float*)d_in[22];
  const float* Wg     = (const float*)d_in[23];
  const float* bg     = (const float*)d_in[24];

  char* ob = (char*)d_out;
  unsigned short* Xg_b  = (unsigned short*)ob;                        // 64 MiB (swz32)
  unsigned short* Xs_b  = (unsigned short*)(ob + (64u << 20));        // 64 MiB (swz32)
  unsigned short* Wc_gs = (unsigned short*)(ob + (128u << 20));       // 2 MiB (swz32)
  unsigned short* Wc_sg = (unsigned short*)(ob + (130u << 20));       // 2 MiB (swz32)
  float* bc_gs = (float*)(ob + (132u << 20));
  float* bc_sg = (float*)(ob + (132u << 20) + 4096);

  unsigned short* Zg = (unsigned short*)d_ws;                         // swz32
  unsigned short* Zs = Zg + (size_t)BROWS * DDIM;                     // swz32
  const bool fast = ws_size >= ((size_t)132 << 20);
  unsigned short* WgB = (unsigned short*)((char*)d_ws + ((size_t)128 << 20)); // swz32

  float* out0 = (float*)d_out;
  float* out1 = out0 + (size_t)BROWS * DDIM;

  cvt_x<<<dim3(65536), dim3(256), 0, stream>>>(graph, smiles, Xg_b, Xs_b);
  bias_combine<<<dim3(8), dim3(256), 0, stream>>>(Wo_gs, bv_gs, bo_gs, Wo_sg, bv_sg, bo_sg,
                                                  bc_gs, bc_sg);
  combine_kernel<<<dim3(64, 2), dim3(256), 0, stream>>>(Wo_gs, Wv_gs, Wo_sg, Wv_sg,
                                                        Wc_gs, Wc_sg);
  if (fast) cvt_wg<<<dim3(2048), dim3(256), 0, stream>>>(Wg, WgB);
  gemm_branch8<<<dim3(2048, 2), dim3(256), 0, stream>>>(Xs_b, Xg_b, Wc_gs, Wc_sg,
                                                        bc_gs, bc_sg, Zg, Zs);
  ln_kernel<<<dim3(16384), dim3(256), 0, stream>>>(Zg, ln_gg, ln_gb, ln_sg, ln_sb);
  if (fast)
    gemm_gate8<<<dim3(2048), dim3(256), 0, stream>>>(Zg, Zs, WgB, bg, out0, out1);
  else
    gemm_gate_f32<<<dim3(2048), dim3(256), 0, stream>>>(Zg, Zs, Wg, bg, out0, out1);
}

// Round 18
// 708.291 us; speedup vs baseline: 1.0121x; 1.0121x over previous
//
#include <hip/hip_runtime.h>

#define BROWS 32768
#define DDIM 1024

typedef __bf16 bf16x8v __attribute__((ext_vector_type(8)));
typedef float f32x4v __attribute__((ext_vector_type(4)));

__device__ __forceinline__ float bf2f(unsigned short u) {
  union { unsigned int i; float f; } w; w.i = ((unsigned int)u) << 16; return w.f;
}
__device__ __forceinline__ unsigned short f2bf(float f) {
  union { float f; unsigned int i; } w; w.f = f;
  w.i += 0x7fffu + ((w.i >> 16) & 1u);   // RNE
  return (unsigned short)(w.i >> 16);
}

__device__ __forceinline__ void gl_lds16(const void* g, void* l) {
  __builtin_amdgcn_global_load_lds((const __attribute__((address_space(1))) void*)g,
                                   (__attribute__((address_space(3))) void*)l, 16, 0, 0);
}

__device__ __forceinline__ int xcd_swz(int bid, int nwg) {
  return (bid & 7) * (nwg >> 3) + (bid >> 3);
}

// Column swizzle within each 64-col block; involution; 16B granular.
__device__ __forceinline__ int swzc(int row, int col) {
  return (col & ~63) | ((col & 63) ^ ((row & 7) << 3));
}

// graph & smiles f32 -> bf16, PRE-SWIZZLED layout.
__global__ __launch_bounds__(256) void cvt_x(const float* __restrict__ g,
                                             const float* __restrict__ s,
                                             unsigned short* __restrict__ xg,
                                             unsigned short* __restrict__ xs) {
  const size_t N = (size_t)BROWS * DDIM;
  size_t i = ((size_t)blockIdx.x * 256 + threadIdx.x) * 4;
  const float* src = (i < N) ? g : s;
  unsigned short* dst = (i < N) ? xg : xs;
  size_t off = (i < N) ? i : i - N;
  int row = (int)(off >> 10), col = (int)(off & 1023);
  float4 v = *(const float4*)&src[off];
  union { uint2 q; unsigned short h[4]; } u;
  u.h[0] = f2bf(v.x); u.h[1] = f2bf(v.y); u.h[2] = f2bf(v.z); u.h[3] = f2bf(v.w);
  *(uint2*)&dst[(size_t)row * DDIM + swzc(row, col)] = u.q;
}

// Wg f32 [1024][2048] -> bf16, PRE-SWIZZLED.
__global__ __launch_bounds__(256) void cvt_wg(const float* __restrict__ s,
                                              unsigned short* __restrict__ d) {
  int i = (blockIdx.x * 256 + threadIdx.x) * 4;
  int row = i >> 11, col = i & 2047;
  float4 v = *(const float4*)&s[i];
  union { uint2 q; unsigned short h[4]; } u;
  u.h[0] = f2bf(v.x); u.h[1] = f2bf(v.y); u.h[2] = f2bf(v.z); u.h[3] = f2bf(v.w);
  *(uint2*)&d[(size_t)row * 2048 + swzc(row, col)] = u.q;
}

// bc = Wo @ bv + bo
__global__ __launch_bounds__(256) void bias_combine(
    const float* __restrict__ Wo_gs, const float* __restrict__ bv_gs,
    const float* __restrict__ bo_gs,
    const float* __restrict__ Wo_sg, const float* __restrict__ bv_sg,
    const float* __restrict__ bo_sg,
    float* __restrict__ bc_gs, float* __restrict__ bc_sg) {
  int gid = blockIdx.x * 256 + threadIdx.x;
  int pair = gid >> 10, j = gid & 1023;
  const float* Wo = pair ? Wo_sg : Wo_gs;
  const float* bv = pair ? bv_sg : bv_gs;
  const float* bo = pair ? bo_sg : bo_gs;
  float s = 0.f;
  for (int k = 0; k < DDIM; k += 4) {
    float4 w = *(const float4*)&Wo[(size_t)j * DDIM + k];
    float4 b = *(const float4*)&bv[k];
    s += w.x * b.x + w.y * b.y + w.z * b.z + w.w * b.w;
  }
  float* bc = pair ? bc_sg : bc_gs;
  bc[j] = s + bo[j];
}

// f32 -> bf16 [128][32] LDS tile (combine kernel, linear layout).
__device__ __forceinline__ void stage_f32_32(const float* __restrict__ src, int ldk,
                                             int row0, int k0, unsigned short* lds, int tid) {
  const int sr = tid >> 2, sc = (tid & 3) * 8;
#pragma unroll
  for (int h = 0; h < 2; ++h) {
    const float* g = &src[(size_t)(row0 + h * 64 + sr) * ldk + k0 + sc];
    float4 va = ((const float4*)g)[0];
    float4 vb = ((const float4*)g)[1];
    union { uint4 q; unsigned short hh[8]; } u;
    u.hh[0] = f2bf(va.x); u.hh[1] = f2bf(va.y); u.hh[2] = f2bf(va.z); u.hh[3] = f2bf(va.w);
    u.hh[4] = f2bf(vb.x); u.hh[5] = f2bf(vb.y); u.hh[6] = f2bf(vb.z); u.hh[7] = f2bf(vb.w);
    *(uint4*)&lds[(h * 64 + sr) * 32 + sc] = u.q;
  }
}

__device__ __forceinline__ void mfma_tile32(const unsigned short* As, const unsigned short* Bs,
                                            int ab, int bb, f32x4v acc[4][4]) {
  const bf16x8v* Av = reinterpret_cast<const bf16x8v*>(As);
  const bf16x8v* Bv = reinterpret_cast<const bf16x8v*>(Bs);
  bf16x8v af[4], bfr[4];
#pragma unroll
  for (int m = 0; m < 4; ++m) af[m] = Av[ab + m * 64];
#pragma unroll
  for (int n = 0; n < 4; ++n) bfr[n] = Bv[bb + n * 64];
#pragma unroll
  for (int m = 0; m < 4; ++m)
#pragma unroll
    for (int n = 0; n < 4; ++n)
      acc[m][n] = __builtin_amdgcn_mfma_f32_16x16x32_bf16(af[m], bfr[n], acc[m][n], 0, 0, 0);
}

// Wc = Wo @ Wv (1024^3 NN, f32 in) — writes Wc PRE-SWIZZLED.
__global__ __launch_bounds__(256) void combine_kernel(
    const float* __restrict__ Wo_gs, const float* __restrict__ Wv_gs,
    const float* __restrict__ Wo_sg, const float* __restrict__ Wv_sg,
    unsigned short* __restrict__ Wc_gs, unsigned short* __restrict__ Wc_sg) {
  const int pair = blockIdx.y;
  const float* Wo = pair ? Wo_sg : Wo_gs;
  const float* Wv = pair ? Wv_sg : Wv_gs;
  unsigned short* Wc = pair ? Wc_sg : Wc_gs;
  const int mt = blockIdx.x >> 3, nt = blockIdx.x & 7;
  const int row0 = mt * 128, col0 = nt * 128;

  __shared__ __align__(16) unsigned short As[128 * 32];
  __shared__ __align__(16) unsigned short Bt[128 * 32];

  const int tid = threadIdx.x;
  const int lane = tid & 63, wave = tid >> 6;
  const int wr = wave >> 1, wc = wave & 1;
  const int lr = lane & 15, lk = lane >> 4;

  f32x4v acc[4][4] = {};
  const int ab = (wr * 64 + lr) * 4 + lk;
  const int bb = (wc * 64 + lr) * 4 + lk;

  for (int tt = 0; tt < 32; ++tt) {
    const int t0 = tt * 32;
    __syncthreads();
    stage_f32_32(Wo, DDIM, row0, t0, As, tid);
#pragma unroll
    for (int h = 0; h < 2; ++h) {
      int chunk = h * 256 + tid;
      int t = chunk >> 4;
      int c8 = (chunk & 15) * 8;
      const float* g = &Wv[(size_t)(t0 + t) * DDIM + col0 + c8];
      float4 va = ((const float4*)g)[0];
      float4 vb = ((const float4*)g)[1];
      float vv[8] = {va.x, va.y, va.z, va.w, vb.x, vb.y, vb.z, vb.w};
#pragma unroll
      for (int e = 0; e < 8; ++e) Bt[(c8 + e) * 32 + t] = f2bf(vv[e]);
    }
    __syncthreads();
    mfma_tile32(As, Bt, ab, bb, acc);
  }

#pragma unroll
  for (int n = 0; n < 4; ++n) {
    int col = col0 + wc * 64 + n * 16 + lr;
#pragma unroll
    for (int m = 0; m < 4; ++m) {
      int rbase = row0 + wr * 64 + m * 16 + lk * 4;
#pragma unroll
      for (int r = 0; r < 4; ++r)
        Wc[(size_t)(rbase + r) * DDIM + swzc(rbase + r, col)] = f2bf(acc[m][n][r]);
    }
  }
}

// ====== 128x128 pipelined GEMM, counted vmcnt, 2 blocks/CU (80 KB LDS) ======
// 4 waves (2Mx2N), per-wave 64x64 acc[4][4]. A: 3 slots [128][64] (dist 2);
// B: 2 slots (dist 1). Per K-tile: vmcnt(4) -> s_barrier -> issue B(kt+1)x4 +
// A(kt+2)x4 -> 16 frag reads -> setprio{32 MFMA}. Ledger: at kt, outstanding =
// A(kt)4,B(kt)4,A(kt+1)4 (FIFO); vmcnt(4) retires A(kt),B(kt), keeps A(kt+1).
// WAR-free: write slots != read slot; ds_reads drained via MFMA deps pre-barrier.

// Z = bf16( Xb @ Wc^T + bc + residb ), all operand arrays pre-swizzled.
__global__ __launch_bounds__(256, 2) void gemm_branch8(
    const unsigned short* __restrict__ Xs_b, const unsigned short* __restrict__ Xg_b,
    const unsigned short* __restrict__ Wc_gs, const unsigned short* __restrict__ Wc_sg,
    const float* __restrict__ bc_gs, const float* __restrict__ bc_sg,
    unsigned short* __restrict__ Zg, unsigned short* __restrict__ Zs) {
  const int pair = blockIdx.y;
  const unsigned short* X = pair ? Xg_b : Xs_b;
  const unsigned short* residb = pair ? Xs_b : Xg_b;
  const unsigned short* Wc = pair ? Wc_sg : Wc_gs;
  const float* bc = pair ? bc_sg : bc_gs;
  unsigned short* Z = pair ? Zs : Zg;

  const int bid = xcd_swz(blockIdx.x, 2048);
  const int mt = bid >> 3, nt = bid & 7;
  const int row0 = mt * 128, col0 = nt * 128;
  const int NT = 16;

  __shared__ __align__(16) unsigned short As[3][128 * 64];   // 48 KB
  __shared__ __align__(16) unsigned short Bs[2][128 * 64];   // 32 KB

  const int tid = threadIdx.x;
  const int lane = tid & 63, wave = tid >> 6;
  const int wm = wave >> 1, wn = wave & 1;
  const int lr = lane & 15, lk = lane >> 4;

  f32x4v acc[4][4] = {};

  auto stageB = [&](int kt) {
#pragma unroll
    for (int r = 0; r < 4; ++r) {
      int idx = r * 2048 + tid * 8;
      int row = idx >> 6, ch = (tid & 7) * 8;
      gl_lds16(&Wc[(size_t)(col0 + row) * DDIM + kt * 64 + ch], &Bs[kt & 1][idx]);
    }
  };
  auto stageA = [&](int kt) {
    int slot = kt - (kt / 3) * 3;
#pragma unroll
    for (int r = 0; r < 4; ++r) {
      int idx = r * 2048 + tid * 8;
      int row = idx >> 6, ch = (tid & 7) * 8;
      gl_lds16(&X[(size_t)(row0 + row) * DDIM + kt * 64 + ch], &As[slot][idx]);
    }
  };

  stageB(0); stageA(0); stageA(1);

  for (int kt = 0; kt < NT; ++kt) {
    if (kt < NT - 1) asm volatile("s_waitcnt vmcnt(4)" ::: "memory");
    else             asm volatile("s_waitcnt vmcnt(0)" ::: "memory");
    asm volatile("s_barrier" ::: "memory");
    if (kt + 1 < NT) stageB(kt + 1);
    if (kt + 2 < NT) stageA(kt + 2);

    const unsigned short* Ak = As[kt - (kt / 3) * 3];
    const unsigned short* Bk = Bs[kt & 1];
    bf16x8v bv[4][2], av[4][2];
#pragma unroll
    for (int n = 0; n < 4; ++n)
#pragma unroll
      for (int s = 0; s < 2; ++s) {
        int row = wn * 64 + n * 16 + lr;
        bv[n][s] = *(const bf16x8v*)&Bk[row * 64 + (((s * 4 + lk) ^ (row & 7)) * 8)];
      }
#pragma unroll
    for (int m = 0; m < 4; ++m)
#pragma unroll
      for (int s = 0; s < 2; ++s) {
        int row = wm * 64 + m * 16 + lr;
        av[m][s] = *(const bf16x8v*)&Ak[row * 64 + (((s * 4 + lk) ^ (row & 7)) * 8)];
      }
    __builtin_amdgcn_s_setprio(1);
#pragma unroll
    for (int s = 0; s < 2; ++s)
#pragma unroll
      for (int m = 0; m < 4; ++m)
#pragma unroll
        for (int n = 0; n < 4; ++n)
          acc[m][n] = __builtin_amdgcn_mfma_f32_16x16x32_bf16(av[m][s], bv[n][s],
                                                              acc[m][n], 0, 0, 0);
    __builtin_amdgcn_s_setprio(0);
  }

#pragma unroll
  for (int n = 0; n < 4; ++n) {
    int col = col0 + wn * 64 + n * 16 + lr;
    float bcv = bc[col];
#pragma unroll
    for (int m = 0; m < 4; ++m) {
      int rb = row0 + wm * 64 + m * 16 + lk * 4;
#pragma unroll
      for (int r = 0; r < 4; ++r) {
        int row = rb + r;
        size_t idx = (size_t)row * DDIM + swzc(row, col);
        Z[idx] = f2bf(acc[m][n][r] + bcv + bf2f(residb[idx]));
      }
    }
  }
}

// gate = sigmoid([fg,fs] @ WgB^T + bg); f32 out at true columns.
__global__ __launch_bounds__(256, 2) void gemm_gate8(
    const unsigned short* __restrict__ fg, const unsigned short* __restrict__ fs,
    const unsigned short* __restrict__ WgB, const float* __restrict__ bg,
    float* __restrict__ out0, float* __restrict__ out1) {
  const int bid = xcd_swz(blockIdx.x, 2048);
  const int mt = bid >> 3, nt = bid & 7;
  const int row0 = mt * 128, col0 = nt * 128;
  const int NT = 32;

  __shared__ __align__(16) unsigned short As[3][128 * 64];
  __shared__ __align__(16) unsigned short Bs[2][128 * 64];

  const int tid = threadIdx.x;
  const int lane = tid & 63, wave = tid >> 6;
  const int wm = wave >> 1, wn = wave & 1;
  const int lr = lane & 15, lk = lane >> 4;

  f32x4v acc[4][4] = {};

  auto stageB = [&](int kt) {
#pragma unroll
    for (int r = 0; r < 4; ++r) {
      int idx = r * 2048 + tid * 8;
      int row = idx >> 6, ch = (tid & 7) * 8;
      gl_lds16(&WgB[(size_t)(col0 + row) * 2048 + kt * 64 + ch], &Bs[kt & 1][idx]);
    }
  };
  auto stageA = [&](int kt) {
    const unsigned short* asrc = (kt < 16) ? fg : fs;
    int ak0 = (kt & 15) * 64;
    int slot = kt - (kt / 3) * 3;
#pragma unroll
    for (int r = 0; r < 4; ++r) {
      int idx = r * 2048 + tid * 8;
      int row = idx >> 6, ch = (tid & 7) * 8;
      gl_lds16(&asrc[(size_t)(row0 + row) * DDIM + ak0 + ch], &As[slot][idx]);
    }
  };

  stageB(0); stageA(0); stageA(1);

  for (int kt = 0; kt < NT; ++kt) {
    if (kt < NT - 1) asm volatile("s_waitcnt vmcnt(4)" ::: "memory");
    else             asm volatile("s_waitcnt vmcnt(0)" ::: "memory");
    asm volatile("s_barrier" ::: "memory");
    if (kt + 1 < NT) stageB(kt + 1);
    if (kt + 2 < NT) stageA(kt + 2);

    const unsigned short* Ak = As[kt - (kt / 3) * 3];
    const unsigned short* Bk = Bs[kt & 1];
    bf16x8v bv[4][2], av[4][2];
#pragma unroll
    for (int n = 0; n < 4; ++n)
#pragma unroll
      for (int s = 0; s < 2; ++s) {
        int row = wn * 64 + n * 16 + lr;
        bv[n][s] = *(const bf16x8v*)&Bk[row * 64 + (((s * 4 + lk) ^ (row & 7)) * 8)];
      }
#pragma unroll
    for (int m = 0; m < 4; ++m)
#pragma unroll
      for (int s = 0; s < 2; ++s) {
        int row = wm * 64 + m * 16 + lr;
        av[m][s] = *(const bf16x8v*)&Ak[row * 64 + (((s * 4 + lk) ^ (row & 7)) * 8)];
      }
    __builtin_amdgcn_s_setprio(1);
#pragma unroll
    for (int s = 0; s < 2; ++s)
#pragma unroll
      for (int m = 0; m < 4; ++m)
#pragma unroll
        for (int n = 0; n < 4; ++n)
          acc[m][n] = __builtin_amdgcn_mfma_f32_16x16x32_bf16(av[m][s], bv[n][s],
                                                              acc[m][n], 0, 0, 0);
    __builtin_amdgcn_s_setprio(0);
  }

#pragma unroll
  for (int n = 0; n < 4; ++n) {
    int col = col0 + wn * 64 + n * 16 + lr;
    float bgv = bg[col];
#pragma unroll
    for (int m = 0; m < 4; ++m) {
      int rb = row0 + wm * 64 + m * 16 + lk * 4;
#pragma unroll
      for (int r = 0; r < 4; ++r) {
        int row = rb + r;
        size_t sidx = (size_t)row * DDIM + swzc(row, col);
        size_t tidx = (size_t)row * DDIM + col;
        float g = 1.f / (1.f + __expf(-(acc[m][n][r] + bgv)));
        float a = bf2f(fg[sidx]), b = bf2f(fs[sidx]);
        out0[tidx] = g * a + (1.f - g) * b;
        out1[tidx] = g;
      }
    }
  }
}

// In-place LayerNorm over swizzled Z rows (gamma/beta index XORed).
__global__ __launch_bounds__(256) void ln_kernel(
    unsigned short* __restrict__ Z,
    const float* __restrict__ gam_g, const float* __restrict__ bet_g,
    const float* __restrict__ gam_s, const float* __restrict__ bet_s) {
  int row = blockIdx.x * 4 + (threadIdx.x >> 6);
  int lane = threadIdx.x & 63;
  const float* gam = (row < BROWS) ? gam_g : gam_s;
  const float* bet = (row < BROWS) ? bet_g : bet_s;
  unsigned short* zr = Z + (size_t)row * DDIM;

  uint4 v0 = *(const uint4*)(zr + lane * 8);
  uint4 v1 = *(const uint4*)(zr + 512 + lane * 8);
  const unsigned short* u0 = (const unsigned short*)&v0;
  const unsigned short* u1 = (const unsigned short*)&v1;
  float x[16];
  float s = 0.f, sq = 0.f;
#pragma unroll
  for (int e = 0; e < 8; ++e) { x[e] = bf2f(u0[e]); x[8 + e] = bf2f(u1[e]); }
#pragma unroll
  for (int i = 0; i < 16; ++i) { s += x[i]; sq += x[i] * x[i]; }
#pragma unroll
  for (int o = 32; o; o >>= 1) { s += __shfl_xor(s, o); sq += __shfl_xor(sq, o); }
  float mu = s * (1.f / 1024.f);
  float var = sq * (1.f / 1024.f) - mu * mu;
  float rstd = rsqrtf(var + 1e-5f);

  int lane2 = (lane & ~7) | ((lane & 7) ^ (row & 7));
  float4 g0 = *(const float4*)(gam + lane2 * 8);
  float4 g1 = *(const float4*)(gam + lane2 * 8 + 4);
  float4 g2 = *(const float4*)(gam + 512 + lane2 * 8);
  float4 g3 = *(const float4*)(gam + 512 + lane2 * 8 + 4);
  float4 b0 = *(const float4*)(bet + lane2 * 8);
  float4 b1 = *(const float4*)(bet + lane2 * 8 + 4);
  float4 b2 = *(const float4*)(bet + 512 + lane2 * 8);
  float4 b3 = *(const float4*)(bet + 512 + lane2 * 8 + 4);
  float gg[16] = {g0.x,g0.y,g0.z,g0.w,g1.x,g1.y,g1.z,g1.w,
                  g2.x,g2.y,g2.z,g2.w,g3.x,g3.y,g3.z,g3.w};
  float bb[16] = {b0.x,b0.y,b0.z,b0.w,b1.x,b1.y,b1.z,b1.w,
                  b2.x,b2.y,b2.z,b2.w,b3.x,b3.y,b3.z,b3.w};

  union { uint4 q; unsigned short h[8]; } o0, o1;
#pragma unroll
  for (int e = 0; e < 8; ++e) {
    o0.h[e] = f2bf((x[e] - mu) * rstd * gg[e] + bb[e]);
    o1.h[e] = f2bf((x[8 + e] - mu) * rstd * gg[8 + e] + bb[8 + e]);
  }
  *(uint4*)(zr + lane * 8) = o0.q;
  *(uint4*)(zr + 512 + lane * 8) = o1.q;
}

// Fallback gate (d_ws < 132 MiB): r11 structure, B reg-staged from f32 Wg.
__global__ __launch_bounds__(256) void gemm_gate_f32(
    const unsigned short* __restrict__ fg, const unsigned short* __restrict__ fs,
    const float* __restrict__ Wg, const float* __restrict__ bg,
    float* __restrict__ out0, float* __restrict__ out1) {
  const int bid = xcd_swz(blockIdx.x, 2048);
  const int mt = bid >> 3, nt = bid & 7;
  const int row0 = mt * 128, col0 = nt * 128;

  __shared__ __align__(16) unsigned short As[128 * 64];
  __shared__ __align__(16) unsigned short Bsh[128 * 64];

  const int tid = threadIdx.x;
  const int lane = tid & 63, wave = tid >> 6;
  const int wr = wave >> 1, wc = wave & 1;
  const int lr = lane & 15, lk = lane >> 4;

  f32x4v acc[4][4] = {};

  for (int kt = 0; kt < 32; ++kt) {
    const unsigned short* Asrc = (kt < 16) ? fg : fs;
    const int k0 = (kt & 15) * 64;
    const int kw = kt * 64;
    __syncthreads();
#pragma unroll
    for (int h = 0; h < 4; ++h) {
      int row = h * 32 + (tid >> 3);
      gl_lds16(&Asrc[(size_t)(row0 + row) * DDIM + k0 + (tid & 7) * 8], &As[h * 2048 + tid * 8]);
    }
#pragma unroll
    for (int h = 0; h < 4; ++h) {
      int row = h * 32 + (tid >> 3), c16 = tid & 7;
      const float* gsrc = &Wg[(size_t)(col0 + row) * 2048 + kw + c16 * 8];
      float4 va = ((const float4*)gsrc)[0];
      float4 vb = ((const float4*)gsrc)[1];
      union { uint4 q; unsigned short hh[8]; } u;
      u.hh[0] = f2bf(va.x); u.hh[1] = f2bf(va.y); u.hh[2] = f2bf(va.z); u.hh[3] = f2bf(va.w);
      u.hh[4] = f2bf(vb.x); u.hh[5] = f2bf(vb.y); u.hh[6] = f2bf(vb.z); u.hh[7] = f2bf(vb.w);
      *(uint4*)&Bsh[(row * 8 + (c16 ^ (row & 7))) * 8] = u.q;
    }
    __syncthreads();
    const bf16x8v* Av = reinterpret_cast<const bf16x8v*>(As);
    const bf16x8v* Bv = reinterpret_cast<const bf16x8v*>(Bsh);
    const int xr = lr & 7;
#pragma unroll
    for (int s = 0; s < 2; ++s) {
      const int u = (s * 4 + lk) ^ xr;
      bf16x8v af[4], bfr[4];
#pragma unroll
      for (int m = 0; m < 4; ++m) af[m] = Av[(wr * 64 + m * 16 + lr) * 8 + u];
#pragma unroll
      for (int n = 0; n < 4; ++n) bfr[n] = Bv[(wc * 64 + n * 16 + lr) * 8 + u];
#pragma unroll
      for (int m = 0; m < 4; ++m)
#pragma unroll
        for (int n = 0; n < 4; ++n)
          acc[m][n] = __builtin_amdgcn_mfma_f32_16x16x32_bf16(af[m], bfr[n], acc[m][n], 0, 0, 0);
    }
  }

#pragma unroll
  for (int n = 0; n < 4; ++n) {
    int col = col0 + wc * 64 + n * 16 + lr;
    float bgv = bg[col];
#pragma unroll
    for (int m = 0; m < 4; ++m) {
      int rbase = row0 + wr * 64 + m * 16 + lk * 4;
#pragma unroll
      for (int r = 0; r < 4; ++r) {
        int row = rbase + r;
        size_t sidx = (size_t)row * DDIM + swzc(row, col);
        size_t tidx = (size_t)row * DDIM + col;
        float g = 1.f / (1.f + __expf(-(acc[m][n][r] + bgv)));
        float a = bf2f(fg[sidx]), b = bf2f(fs[sidx]);
        out0[tidx] = g * a + (1.f - g) * b;
        out1[tidx] = g;
      }
    }
  }
}

extern "C" void kernel_launch(void* const* d_in, const int* in_sizes, int n_in,
                              void* d_out, int out_size, void* d_ws, size_t ws_size,
                              hipStream_t stream) {
  const float* graph  = (const float*)d_in[0];
  const float* smiles = (const float*)d_in[1];
  const float* Wv_gs  = (const float*)d_in[5];
  const float* bv_gs  = (const float*)d_in[8];
  const float* Wo_gs  = (const float*)d_in[9];
  const float* bo_gs  = (const float*)d_in[10];
  const float* Wv_sg  = (const float*)d_in[13];
  const float* bv_sg  = (const float*)d_in[16];
  const float* Wo_sg  = (const float*)d_in[17];
  const float* bo_sg  = (const float*)d_in[18];
  const float* ln_gg  = (const float*)d_in[19];
  const float* ln_gb  = (const float*)d_in[20];
  const float* ln_sg  = (const float*)d_in[21];
  const float* ln_sb  = (const float*)d_in[22];
  const float* Wg     = (const float*)d_in[23];
  const float* bg     = (const float*)d_in[24];

  char* ob = (char*)d_out;
  unsigned short* Xg_b  = (unsigned short*)ob;                        // 64 MiB (swz)
  unsigned short* Xs_b  = (unsigned short*)(ob + (64u << 20));        // 64 MiB (swz)
  unsigned short* Wc_gs = (unsigned short*)(ob + (128u << 20));       // 2 MiB (swz)
  unsigned short* Wc_sg = (unsigned short*)(ob + (130u << 20));       // 2 MiB (swz)
  float* bc_gs = (float*)(ob + (132u << 20));
  float* bc_sg = (float*)(ob + (132u << 20) + 4096);

  unsigned short* Zg = (unsigned short*)d_ws;                         // swz
  unsigned short* Zs = Zg + (size_t)BROWS * DDIM;                     // swz
  const bool fast = ws_size >= ((size_t)132 << 20);
  unsigned short* WgB = (unsigned short*)((char*)d_ws + ((size_t)128 << 20)); // swz

  float* out0 = (float*)d_out;
  float* out1 = out0 + (size_t)BROWS * DDIM;

  cvt_x<<<dim3(65536), dim3(256), 0, stream>>>(graph, smiles, Xg_b, Xs_b);
  bias_combine<<<dim3(8), dim3(256), 0, stream>>>(Wo_gs, bv_gs, bo_gs, Wo_sg, bv_sg, bo_sg,
                                                  bc_gs, bc_sg);
  combine_kernel<<<dim3(64, 2), dim3(256), 0, stream>>>(Wo_gs, Wv_gs, Wo_sg, Wv_sg,
                                                        Wc_gs, Wc_sg);
  if (fast) cvt_wg<<<dim3(2048), dim3(256), 0, stream>>>(Wg, WgB);
  gemm_branch8<<<dim3(2048, 2), dim3(256), 0, stream>>>(Xs_b, Xg_b, Wc_gs, Wc_sg,
                                                        bc_gs, bc_sg, Zg, Zs);
  ln_kernel<<<dim3(16384), dim3(256), 0, stream>>>(Zg, ln_gg, ln_gb, ln_sg, ln_sb);
  if (fast)
    gemm_gate8<<<dim3(2048), dim3(256), 0, stream>>>(Zg, Zs, WgB, bg, out0, out1);
  else
    gemm_gate_f32<<<dim3(2048), dim3(256), 0, stream>>>(Zg, Zs, Wg, bg, out0, out1);
}

// Round 19
// 659.116 us; speedup vs baseline: 1.0876x; 1.0746x over previous
//
#include <hip/hip_runtime.h>

#define BROWS 32768
#define DDIM 1024

typedef __bf16 bf16x8v __attribute__((ext_vector_type(8)));
typedef float f32x4v __attribute__((ext_vector_type(4)));

__device__ __forceinline__ float bf2f(unsigned short u) {
  union { unsigned int i; float f; } w; w.i = ((unsigned int)u) << 16; return w.f;
}
__device__ __forceinline__ unsigned short f2bf(float f) {
  union { float f; unsigned int i; } w; w.f = f;
  w.i += 0x7fffu + ((w.i >> 16) & 1u);   // RNE
  return (unsigned short)(w.i >> 16);
}

__device__ __forceinline__ void gl_lds16(const void* g, void* l) {
  __builtin_amdgcn_global_load_lds((const __attribute__((address_space(1))) void*)g,
                                   (__attribute__((address_space(3))) void*)l, 16, 0, 0);
}

__device__ __forceinline__ int xcd_swz(int bid, int nwg) {
  return (bid & 7) * (nwg >> 3) + (bid >> 3);
}

// Column swizzle within each 64-col block; involution; 16B granular.
__device__ __forceinline__ int swzc(int row, int col) {
  return (col & ~63) | ((col & 63) ^ ((row & 7) << 3));
}

// graph & smiles f32 -> bf16, PRE-SWIZZLED layout.
__global__ __launch_bounds__(256) void cvt_x(const float* __restrict__ g,
                                             const float* __restrict__ s,
                                             unsigned short* __restrict__ xg,
                                             unsigned short* __restrict__ xs) {
  const size_t N = (size_t)BROWS * DDIM;
  size_t i = ((size_t)blockIdx.x * 256 + threadIdx.x) * 4;
  const float* src = (i < N) ? g : s;
  unsigned short* dst = (i < N) ? xg : xs;
  size_t off = (i < N) ? i : i - N;
  int row = (int)(off >> 10), col = (int)(off & 1023);
  float4 v = *(const float4*)&src[off];
  union { uint2 q; unsigned short h[4]; } u;
  u.h[0] = f2bf(v.x); u.h[1] = f2bf(v.y); u.h[2] = f2bf(v.z); u.h[3] = f2bf(v.w);
  *(uint2*)&dst[(size_t)row * DDIM + swzc(row, col)] = u.q;
}

// Wg f32 [1024][2048] -> bf16, PRE-SWIZZLED.
__global__ __launch_bounds__(256) void cvt_wg(const float* __restrict__ s,
                                              unsigned short* __restrict__ d) {
  int i = (blockIdx.x * 256 + threadIdx.x) * 4;
  int row = i >> 11, col = i & 2047;
  float4 v = *(const float4*)&s[i];
  union { uint2 q; unsigned short h[4]; } u;
  u.h[0] = f2bf(v.x); u.h[1] = f2bf(v.y); u.h[2] = f2bf(v.z); u.h[3] = f2bf(v.w);
  *(uint2*)&d[(size_t)row * 2048 + swzc(row, col)] = u.q;
}

// bc = Wo @ bv + bo
__global__ __launch_bounds__(256) void bias_combine(
    const float* __restrict__ Wo_gs, const float* __restrict__ bv_gs,
    const float* __restrict__ bo_gs,
    const float* __restrict__ Wo_sg, const float* __restrict__ bv_sg,
    const float* __restrict__ bo_sg,
    float* __restrict__ bc_gs, float* __restrict__ bc_sg) {
  int gid = blockIdx.x * 256 + threadIdx.x;
  int pair = gid >> 10, j = gid & 1023;
  const float* Wo = pair ? Wo_sg : Wo_gs;
  const float* bv = pair ? bv_sg : bv_gs;
  const float* bo = pair ? bo_sg : bo_gs;
  float s = 0.f;
  for (int k = 0; k < DDIM; k += 4) {
    float4 w = *(const float4*)&Wo[(size_t)j * DDIM + k];
    float4 b = *(const float4*)&bv[k];
    s += w.x * b.x + w.y * b.y + w.z * b.z + w.w * b.w;
  }
  float* bc = pair ? bc_sg : bc_gs;
  bc[j] = s + bo[j];
}

// f32 -> bf16 [128][32] LDS tile (combine kernel, linear layout).
__device__ __forceinline__ void stage_f32_32(const float* __restrict__ src, int ldk,
                                             int row0, int k0, unsigned short* lds, int tid) {
  const int sr = tid >> 2, sc = (tid & 3) * 8;
#pragma unroll
  for (int h = 0; h < 2; ++h) {
    const float* g = &src[(size_t)(row0 + h * 64 + sr) * ldk + k0 + sc];
    float4 va = ((const float4*)g)[0];
    float4 vb = ((const float4*)g)[1];
    union { uint4 q; unsigned short hh[8]; } u;
    u.hh[0] = f2bf(va.x); u.hh[1] = f2bf(va.y); u.hh[2] = f2bf(va.z); u.hh[3] = f2bf(va.w);
    u.hh[4] = f2bf(vb.x); u.hh[5] = f2bf(vb.y); u.hh[6] = f2bf(vb.z); u.hh[7] = f2bf(vb.w);
    *(uint4*)&lds[(h * 64 + sr) * 32 + sc] = u.q;
  }
}

__device__ __forceinline__ void mfma_tile32(const unsigned short* As, const unsigned short* Bs,
                                            int ab, int bb, f32x4v acc[4][4]) {
  const bf16x8v* Av = reinterpret_cast<const bf16x8v*>(As);
  const bf16x8v* Bv = reinterpret_cast<const bf16x8v*>(Bs);
  bf16x8v af[4], bfr[4];
#pragma unroll
  for (int m = 0; m < 4; ++m) af[m] = Av[ab + m * 64];
#pragma unroll
  for (int n = 0; n < 4; ++n) bfr[n] = Bv[bb + n * 64];
#pragma unroll
  for (int m = 0; m < 4; ++m)
#pragma unroll
    for (int n = 0; n < 4; ++n)
      acc[m][n] = __builtin_amdgcn_mfma_f32_16x16x32_bf16(af[m], bfr[n], acc[m][n], 0, 0, 0);
}

// Wc = Wo @ Wv (1024^3 NN, f32 in) — writes Wc PRE-SWIZZLED.
__global__ __launch_bounds__(256) void combine_kernel(
    const float* __restrict__ Wo_gs, const float* __restrict__ Wv_gs,
    const float* __restrict__ Wo_sg, const float* __restrict__ Wv_sg,
    unsigned short* __restrict__ Wc_gs, unsigned short* __restrict__ Wc_sg) {
  const int pair = blockIdx.y;
  const float* Wo = pair ? Wo_sg : Wo_gs;
  const float* Wv = pair ? Wv_sg : Wv_gs;
  unsigned short* Wc = pair ? Wc_sg : Wc_gs;
  const int mt = blockIdx.x >> 3, nt = blockIdx.x & 7;
  const int row0 = mt * 128, col0 = nt * 128;

  __shared__ __align__(16) unsigned short As[128 * 32];
  __shared__ __align__(16) unsigned short Bt[128 * 32];

  const int tid = threadIdx.x;
  const int lane = tid & 63, wave = tid >> 6;
  const int wr = wave >> 1, wc = wave & 1;
  const int lr = lane & 15, lk = lane >> 4;

  f32x4v acc[4][4] = {};
  const int ab = (wr * 64 + lr) * 4 + lk;
  const int bb = (wc * 64 + lr) * 4 + lk;

  for (int tt = 0; tt < 32; ++tt) {
    const int t0 = tt * 32;
    __syncthreads();
    stage_f32_32(Wo, DDIM, row0, t0, As, tid);
#pragma unroll
    for (int h = 0; h < 2; ++h) {
      int chunk = h * 256 + tid;
      int t = chunk >> 4;
      int c8 = (chunk & 15) * 8;
      const float* g = &Wv[(size_t)(t0 + t) * DDIM + col0 + c8];
      float4 va = ((const float4*)g)[0];
      float4 vb = ((const float4*)g)[1];
      float vv[8] = {va.x, va.y, va.z, va.w, vb.x, vb.y, vb.z, vb.w};
#pragma unroll
      for (int e = 0; e < 8; ++e) Bt[(c8 + e) * 32 + t] = f2bf(vv[e]);
    }
    __syncthreads();
    mfma_tile32(As, Bt, ab, bb, acc);
  }

#pragma unroll
  for (int n = 0; n < 4; ++n) {
    int col = col0 + wc * 64 + n * 16 + lr;
#pragma unroll
    for (int m = 0; m < 4; ++m) {
      int rbase = row0 + wr * 64 + m * 16 + lk * 4;
#pragma unroll
      for (int r = 0; r < 4; ++r)
        Wc[(size_t)(rbase + r) * DDIM + swzc(rbase + r, col)] = f2bf(acc[m][n][r]);
    }
  }
}

// ====== 128x128 pipelined GEMM, counted vmcnt, 2 blocks/CU, 8 waves/block ======
// 512 thr, 8 waves (4Mx2N), per-wave 32x64 acc[2][4]. A: 3 slots [128][64]
// (dist 2); B: 2 slots (dist 1). LDS 80 KB -> 2 blocks/CU = 16 waves/CU.
// Per K-tile: vmcnt(2) -> s_barrier -> issue B(kt+1)x2 + A(kt+2)x2 -> frag
// reads -> setprio{16 MFMA}. Ledger (FIFO): at kt, outstanding =
// A(kt)2,B(kt)2,A(kt+1)2; vmcnt(2) retires A(kt),B(kt), keeps A(kt+1).

// Z = bf16( Xb @ Wc^T + bc + residb ), all operand arrays pre-swizzled.
__global__ __launch_bounds__(512, 2) void gemm_branch8(
    const unsigned short* __restrict__ Xs_b, const unsigned short* __restrict__ Xg_b,
    const unsigned short* __restrict__ Wc_gs, const unsigned short* __restrict__ Wc_sg,
    const float* __restrict__ bc_gs, const float* __restrict__ bc_sg,
    unsigned short* __restrict__ Zg, unsigned short* __restrict__ Zs) {
  const int pair = blockIdx.y;
  const unsigned short* X = pair ? Xg_b : Xs_b;
  const unsigned short* residb = pair ? Xs_b : Xg_b;
  const unsigned short* Wc = pair ? Wc_sg : Wc_gs;
  const float* bc = pair ? bc_sg : bc_gs;
  unsigned short* Z = pair ? Zs : Zg;

  const int bid = xcd_swz(blockIdx.x, 2048);
  const int mt = bid >> 3, nt = bid & 7;
  const int row0 = mt * 128, col0 = nt * 128;
  const int NT = 16;

  __shared__ __align__(16) unsigned short As[3][128 * 64];   // 48 KB
  __shared__ __align__(16) unsigned short Bs[2][128 * 64];   // 32 KB

  const int tid = threadIdx.x;
  const int lane = tid & 63, wave = tid >> 6;
  const int wm = wave >> 1, wn = wave & 1;
  const int lr = lane & 15, lk = lane >> 4;

  f32x4v acc[2][4] = {};

  auto stageB = [&](int kt) {
#pragma unroll
    for (int r = 0; r < 2; ++r) {
      int idx = r * 4096 + tid * 8;
      int row = idx >> 6, ch = (tid & 7) * 8;
      gl_lds16(&Wc[(size_t)(col0 + row) * DDIM + kt * 64 + ch], &Bs[kt & 1][idx]);
    }
  };
  auto stageA = [&](int kt) {
    int slot = kt - (kt / 3) * 3;
#pragma unroll
    for (int r = 0; r < 2; ++r) {
      int idx = r * 4096 + tid * 8;
      int row = idx >> 6, ch = (tid & 7) * 8;
      gl_lds16(&X[(size_t)(row0 + row) * DDIM + kt * 64 + ch], &As[slot][idx]);
    }
  };

  stageB(0); stageA(0); stageA(1);

  for (int kt = 0; kt < NT; ++kt) {
    if (kt < NT - 1) asm volatile("s_waitcnt vmcnt(2)" ::: "memory");
    else             asm volatile("s_waitcnt vmcnt(0)" ::: "memory");
    asm volatile("s_barrier" ::: "memory");
    if (kt + 1 < NT) stageB(kt + 1);
    if (kt + 2 < NT) stageA(kt + 2);

    const unsigned short* Ak = As[kt - (kt / 3) * 3];
    const unsigned short* Bk = Bs[kt & 1];
    bf16x8v bv[4][2], av[2][2];
#pragma unroll
    for (int n = 0; n < 4; ++n)
#pragma unroll
      for (int s = 0; s < 2; ++s) {
        int row = wn * 64 + n * 16 + lr;
        bv[n][s] = *(const bf16x8v*)&Bk[row * 64 + (((s * 4 + lk) ^ (row & 7)) * 8)];
      }
#pragma unroll
    for (int m = 0; m < 2; ++m)
#pragma unroll
      for (int s = 0; s < 2; ++s) {
        int row = wm * 32 + m * 16 + lr;
        av[m][s] = *(const bf16x8v*)&Ak[row * 64 + (((s * 4 + lk) ^ (row & 7)) * 8)];
      }
    __builtin_amdgcn_s_setprio(1);
#pragma unroll
    for (int s = 0; s < 2; ++s)
#pragma unroll
      for (int m = 0; m < 2; ++m)
#pragma unroll
        for (int n = 0; n < 4; ++n)
          acc[m][n] = __builtin_amdgcn_mfma_f32_16x16x32_bf16(av[m][s], bv[n][s],
                                                              acc[m][n], 0, 0, 0);
    __builtin_amdgcn_s_setprio(0);
  }

#pragma unroll
  for (int n = 0; n < 4; ++n) {
    int col = col0 + wn * 64 + n * 16 + lr;
    float bcv = bc[col];
#pragma unroll
    for (int m = 0; m < 2; ++m) {
      int rb = row0 + wm * 32 + m * 16 + lk * 4;
#pragma unroll
      for (int r = 0; r < 4; ++r) {
        int row = rb + r;
        size_t idx = (size_t)row * DDIM + swzc(row, col);
        Z[idx] = f2bf(acc[m][n][r] + bcv + bf2f(residb[idx]));
      }
    }
  }
}

// gate = sigmoid([fg,fs] @ WgB^T + bg); f32 out at true columns.
__global__ __launch_bounds__(512, 2) void gemm_gate8(
    const unsigned short* __restrict__ fg, const unsigned short* __restrict__ fs,
    const unsigned short* __restrict__ WgB, const float* __restrict__ bg,
    float* __restrict__ out0, float* __restrict__ out1) {
  const int bid = xcd_swz(blockIdx.x, 2048);
  const int mt = bid >> 3, nt = bid & 7;
  const int row0 = mt * 128, col0 = nt * 128;
  const int NT = 32;

  __shared__ __align__(16) unsigned short As[3][128 * 64];
  __shared__ __align__(16) unsigned short Bs[2][128 * 64];

  const int tid = threadIdx.x;
  const int lane = tid & 63, wave = tid >> 6;
  const int wm = wave >> 1, wn = wave & 1;
  const int lr = lane & 15, lk = lane >> 4;

  f32x4v acc[2][4] = {};

  auto stageB = [&](int kt) {
#pragma unroll
    for (int r = 0; r < 2; ++r) {
      int idx = r * 4096 + tid * 8;
      int row = idx >> 6, ch = (tid & 7) * 8;
      gl_lds16(&WgB[(size_t)(col0 + row) * 2048 + kt * 64 + ch], &Bs[kt & 1][idx]);
    }
  };
  auto stageA = [&](int kt) {
    const unsigned short* asrc = (kt < 16) ? fg : fs;
    int ak0 = (kt & 15) * 64;
    int slot = kt - (kt / 3) * 3;
#pragma unroll
    for (int r = 0; r < 2; ++r) {
      int idx = r * 4096 + tid * 8;
      int row = idx >> 6, ch = (tid & 7) * 8;
      gl_lds16(&asrc[(size_t)(row0 + row) * DDIM + ak0 + ch], &As[slot][idx]);
    }
  };

  stageB(0); stageA(0); stageA(1);

  for (int kt = 0; kt < NT; ++kt) {
    if (kt < NT - 1) asm volatile("s_waitcnt vmcnt(2)" ::: "memory");
    else             asm volatile("s_waitcnt vmcnt(0)" ::: "memory");
    asm volatile("s_barrier" ::: "memory");
    if (kt + 1 < NT) stageB(kt + 1);
    if (kt + 2 < NT) stageA(kt + 2);

    const unsigned short* Ak = As[kt - (kt / 3) * 3];
    const unsigned short* Bk = Bs[kt & 1];
    bf16x8v bv[4][2], av[2][2];
#pragma unroll
    for (int n = 0; n < 4; ++n)
#pragma unroll
      for (int s = 0; s < 2; ++s) {
        int row = wn * 64 + n * 16 + lr;
        bv[n][s] = *(const bf16x8v*)&Bk[row * 64 + (((s * 4 + lk) ^ (row & 7)) * 8)];
      }
#pragma unroll
    for (int m = 0; m < 2; ++m)
#pragma unroll
      for (int s = 0; s < 2; ++s) {
        int row = wm * 32 + m * 16 + lr;
        av[m][s] = *(const bf16x8v*)&Ak[row * 64 + (((s * 4 + lk) ^ (row & 7)) * 8)];
      }
    __builtin_amdgcn_s_setprio(1);
#pragma unroll
    for (int s = 0; s < 2; ++s)
#pragma unroll
      for (int m = 0; m < 2; ++m)
#pragma unroll
        for (int n = 0; n < 4; ++n)
          acc[m][n] = __builtin_amdgcn_mfma_f32_16x16x32_bf16(av[m][s], bv[n][s],
                                                              acc[m][n], 0, 0, 0);
    __builtin_amdgcn_s_setprio(0);
  }

#pragma unroll
  for (int n = 0; n < 4; ++n) {
    int col = col0 + wn * 64 + n * 16 + lr;
    float bgv = bg[col];
#pragma unroll
    for (int m = 0; m < 2; ++m) {
      int rb = row0 + wm * 32 + m * 16 + lk * 4;
#pragma unroll
      for (int r = 0; r < 4; ++r) {
        int row = rb + r;
        size_t sidx = (size_t)row * DDIM + swzc(row, col);
        size_t tidx = (size_t)row * DDIM + col;
        float g = 1.f / (1.f + __expf(-(acc[m][n][r] + bgv)));
        float a = bf2f(fg[sidx]), b = bf2f(fs[sidx]);
        out0[tidx] = g * a + (1.f - g) * b;
        out1[tidx] = g;
      }
    }
  }
}

// In-place LayerNorm over swizzled Z rows (gamma/beta index XORed).
__global__ __launch_bounds__(256) void ln_kernel(
    unsigned short* __restrict__ Z,
    const float* __restrict__ gam_g, const float* __restrict__ bet_g,
    const float* __restrict__ gam_s, const float* __restrict__ bet_s) {
  int row = blockIdx.x * 4 + (threadIdx.x >> 6);
  int lane = threadIdx.x & 63;
  const float* gam = (row < BROWS) ? gam_g : gam_s;
  const float* bet = (row < BROWS) ? bet_g : bet_s;
  unsigned short* zr = Z + (size_t)row * DDIM;

  uint4 v0 = *(const uint4*)(zr + lane * 8);
  uint4 v1 = *(const uint4*)(zr + 512 + lane * 8);
  const unsigned short* u0 = (const unsigned short*)&v0;
  const unsigned short* u1 = (const unsigned short*)&v1;
  float x[16];
  float s = 0.f, sq = 0.f;
#pragma unroll
  for (int e = 0; e < 8; ++e) { x[e] = bf2f(u0[e]); x[8 + e] = bf2f(u1[e]); }
#pragma unroll
  for (int i = 0; i < 16; ++i) { s += x[i]; sq += x[i] * x[i]; }
#pragma unroll
  for (int o = 32; o; o >>= 1) { s += __shfl_xor(s, o); sq += __shfl_xor(sq, o); }
  float mu = s * (1.f / 1024.f);
  float var = sq * (1.f / 1024.f) - mu * mu;
  float rstd = rsqrtf(var + 1e-5f);

  int lane2 = (lane & ~7) | ((lane & 7) ^ (row & 7));
  float4 g0 = *(const float4*)(gam + lane2 * 8);
  float4 g1 = *(const float4*)(gam + lane2 * 8 + 4);
  float4 g2 = *(const float4*)(gam + 512 + lane2 * 8);
  float4 g3 = *(const float4*)(gam + 512 + lane2 * 8 + 4);
  float4 b0 = *(const float4*)(bet + lane2 * 8);
  float4 b1 = *(const float4*)(bet + lane2 * 8 + 4);
  float4 b2 = *(const float4*)(bet + 512 + lane2 * 8);
  float4 b3 = *(const float4*)(bet + 512 + lane2 * 8 + 4);
  float gg[16] = {g0.x,g0.y,g0.z,g0.w,g1.x,g1.y,g1.z,g1.w,
                  g2.x,g2.y,g2.z,g2.w,g3.x,g3.y,g3.z,g3.w};
  float bb[16] = {b0.x,b0.y,b0.z,b0.w,b1.x,b1.y,b1.z,b1.w,
                  b2.x,b2.y,b2.z,b2.w,b3.x,b3.y,b3.z,b3.w};

  union { uint4 q; unsigned short h[8]; } o0, o1;
#pragma unroll
  for (int e = 0; e < 8; ++e) {
    o0.h[e] = f2bf((x[e] - mu) * rstd * gg[e] + bb[e]);
    o1.h[e] = f2bf((x[8 + e] - mu) * rstd * gg[8 + e] + bb[8 + e]);
  }
  *(uint4*)(zr + lane * 8) = o0.q;
  *(uint4*)(zr + 512 + lane * 8) = o1.q;
}

// Fallback gate (d_ws < 132 MiB): r11 structure, B reg-staged from f32 Wg.
__global__ __launch_bounds__(256) void gemm_gate_f32(
    const unsigned short* __restrict__ fg, const unsigned short* __restrict__ fs,
    const float* __restrict__ Wg, const float* __restrict__ bg,
    float* __restrict__ out0, float* __restrict__ out1) {
  const int bid = xcd_swz(blockIdx.x, 2048);
  const int mt = bid >> 3, nt = bid & 7;
  const int row0 = mt * 128, col0 = nt * 128;

  __shared__ __align__(16) unsigned short As[128 * 64];
  __shared__ __align__(16) unsigned short Bsh[128 * 64];

  const int tid = threadIdx.x;
  const int lane = tid & 63, wave = tid >> 6;
  const int wr = wave >> 1, wc = wave & 1;
  const int lr = lane & 15, lk = lane >> 4;

  f32x4v acc[4][4] = {};

  for (int kt = 0; kt < 32; ++kt) {
    const unsigned short* Asrc = (kt < 16) ? fg : fs;
    const int k0 = (kt & 15) * 64;
    const int kw = kt * 64;
    __syncthreads();
#pragma unroll
    for (int h = 0; h < 4; ++h) {
      int row = h * 32 + (tid >> 3);
      gl_lds16(&Asrc[(size_t)(row0 + row) * DDIM + k0 + (tid & 7) * 8], &As[h * 2048 + tid * 8]);
    }
#pragma unroll
    for (int h = 0; h < 4; ++h) {
      int row = h * 32 + (tid >> 3), c16 = tid & 7;
      const float* gsrc = &Wg[(size_t)(col0 + row) * 2048 + kw + c16 * 8];
      float4 va = ((const float4*)gsrc)[0];
      float4 vb = ((const float4*)gsrc)[1];
      union { uint4 q; unsigned short hh[8]; } u;
      u.hh[0] = f2bf(va.x); u.hh[1] = f2bf(va.y); u.hh[2] = f2bf(va.z); u.hh[3] = f2bf(va.w);
      u.hh[4] = f2bf(vb.x); u.hh[5] = f2bf(vb.y); u.hh[6] = f2bf(vb.z); u.hh[7] = f2bf(vb.w);
      *(uint4*)&Bsh[(row * 8 + (c16 ^ (row & 7))) * 8] = u.q;
    }
    __syncthreads();
    const bf16x8v* Av = reinterpret_cast<const bf16x8v*>(As);
    const bf16x8v* Bv = reinterpret_cast<const bf16x8v*>(Bsh);
    const int xr = lr & 7;
#pragma unroll
    for (int s = 0; s < 2; ++s) {
      const int u = (s * 4 + lk) ^ xr;
      bf16x8v af[4], bfr[4];
#pragma unroll
      for (int m = 0; m < 4; ++m) af[m] = Av[(wr * 64 + m * 16 + lr) * 8 + u];
#pragma unroll
      for (int n = 0; n < 4; ++n) bfr[n] = Bv[(wc * 64 + n * 16 + lr) * 8 + u];
#pragma unroll
      for (int m = 0; m < 4; ++m)
#pragma unroll
        for (int n = 0; n < 4; ++n)
          acc[m][n] = __builtin_amdgcn_mfma_f32_16x16x32_bf16(af[m], bfr[n], acc[m][n], 0, 0, 0);
    }
  }

#pragma unroll
  for (int n = 0; n < 4; ++n) {
    int col = col0 + wc * 64 + n * 16 + lr;
    float bgv = bg[col];
#pragma unroll
    for (int m = 0; m < 4; ++m) {
      int rbase = row0 + wr * 64 + m * 16 + lk * 4;
#pragma unroll
      for (int r = 0; r < 4; ++r) {
        int row = rbase + r;
        size_t sidx = (size_t)row * DDIM + swzc(row, col);
        size_t tidx = (size_t)row * DDIM + col;
        float g = 1.f / (1.f + __expf(-(acc[m][n][r] + bgv)));
        float a = bf2f(fg[sidx]), b = bf2f(fs[sidx]);
        out0[tidx] = g * a + (1.f - g) * b;
        out1[tidx] = g;
      }
    }
  }
}

extern "C" void kernel_launch(void* const* d_in, const int* in_sizes, int n_in,
                              void* d_out, int out_size, void* d_ws, size_t ws_size,
                              hipStream_t stream) {
  const float* graph  = (const float*)d_in[0];
  const float* smiles = (const float*)d_in[1];
  const float* Wv_gs  = (const float*)d_in[5];
  const float* bv_gs  = (const float*)d_in[8];
  const float* Wo_gs  = (const float*)d_in[9];
  const float* bo_gs  = (const float*)d_in[10];
  const float* Wv_sg  = (const float*)d_in[13];
  const float* bv_sg  = (const float*)d_in[16];
  const float* Wo_sg  = (const float*)d_in[17];
  const float* bo_sg  = (const float*)d_in[18];
  const float* ln_gg  = (const float*)d_in[19];
  const float* ln_gb  = (const float*)d_in[20];
  const float* ln_sg  = (const float*)d_in[21];
  const float* ln_sb  = (const float*)d_in[22];
  const float* Wg     = (const float*)d_in[23];
  const float* bg     = (const float*)d_in[24];

  char* ob = (char*)d_out;
  unsigned short* Xg_b  = (unsigned short*)ob;                        // 64 MiB (swz)
  unsigned short* Xs_b  = (unsigned short*)(ob + (64u << 20));        // 64 MiB (swz)
  unsigned short* Wc_gs = (unsigned short*)(ob + (128u << 20));       // 2 MiB (swz)
  unsigned short* Wc_sg = (unsigned short*)(ob + (130u << 20));       // 2 MiB (swz)
  float* bc_gs = (float*)(ob + (132u << 20));
  float* bc_sg = (float*)(ob + (132u << 20) + 4096);

  unsigned short* Zg = (unsigned short*)d_ws;                         // swz
  unsigned short* Zs = Zg + (size_t)BROWS * DDIM;                     // swz
  const bool fast = ws_size >= ((size_t)132 << 20);
  unsigned short* WgB = (unsigned short*)((char*)d_ws + ((size_t)128 << 20)); // swz

  float* out0 = (float*)d_out;
  float* out1 = out0 + (size_t)BROWS * DDIM;

  cvt_x<<<dim3(65536), dim3(256), 0, stream>>>(graph, smiles, Xg_b, Xs_b);
  bias_combine<<<dim3(8), dim3(256), 0, stream>>>(Wo_gs, bv_gs, bo_gs, Wo_sg, bv_sg, bo_sg,
                                                  bc_gs, bc_sg);
  combine_kernel<<<dim3(64, 2), dim3(256), 0, stream>>>(Wo_gs, Wv_gs, Wo_sg, Wv_sg,
                                                        Wc_gs, Wc_sg);
  if (fast) cvt_wg<<<dim3(2048), dim3(256), 0, stream>>>(Wg, WgB);
  gemm_branch8<<<dim3(2048, 2), dim3(512), 0, stream>>>(Xs_b, Xg_b, Wc_gs, Wc_sg,
                                                        bc_gs, bc_sg, Zg, Zs);
  ln_kernel<<<dim3(16384), dim3(256), 0, stream>>>(Zg, ln_gg, ln_gb, ln_sg, ln_sb);
  if (fast)
    gemm_gate8<<<dim3(2048), dim3(512), 0, stream>>>(Zg, Zs, WgB, bg, out0, out1);
  else
    gemm_gate_f32<<<dim3(2048), dim3(256), 0, stream>>>(Zg, Zs, Wg, bg, out0, out1);
}